// Round 13
// baseline (660.877 us; speedup 1.0000x reference)
//
#include <hip/hip_runtime.h>
#include <hip/hip_cooperative_groups.h>

namespace cg = cooperative_groups;

#define NN 20000
#define EE 320000
#define FIN 200
#define HH 128
#define CC 10
#define GG 100
#define BN_EPS 1e-5f
#define RPB 80          // rows per block; 250 blocks x 80 = 20000 exact

typedef __attribute__((ext_vector_type(8))) short bf16x8;
typedef __attribute__((ext_vector_type(4))) float f32x4;

__device__ __forceinline__ ushort bf16rn(float x) {
    uint u = __float_as_uint(x);
    u += 0x7FFFu + ((u >> 16) & 1u);
    return (ushort)(u >> 16);
}

// Fragment-major packing (verified R11/R12):
// elem (r,k) -> ((r>>4)*(K/32) + (k>>5))*512 + (((k>>3)&3)*16 + (r&15))*8 + (k&7)

// ---------------------------------------------------------------------------
// device phase bodies (verbatim ports of the R12-verified kernels)
// ---------------------------------------------------------------------------
template<int KSTEPS>
__device__ __forceinline__
void dev_gemm_pk(const ushort* __restrict__ Aph, const ushort* __restrict__ Apl,
                 const ushort* __restrict__ Wph, const ushort* __restrict__ Wpl,
                 const float* __restrict__ bias,
                 float* __restrict__ Croot, float* __restrict__ Crel)
{
    const int wid  = threadIdx.x >> 6;
    const int lane = threadIdx.x & 63;
    const int l15  = lane & 15;
    const int matsel = wid >> 2;
    const int ncol = (wid & 3) * 32;
    const int wrg0 = matsel * 8 + (ncol >> 4);
    const int rowb = (lane >> 4) * 4;
    const int rbase0 = blockIdx.x * RPB;

    bf16x8 wh[2][KSTEPS], wl[2][KSTEPS];
    #pragma unroll
    for (int nf = 0; nf < 2; ++nf) {
        const size_t wbase = (size_t)(wrg0 + nf) * KSTEPS * 512;
        #pragma unroll
        for (int ks = 0; ks < KSTEPS; ++ks) {
            wh[nf][ks] = *(const bf16x8*)&Wph[wbase + (size_t)(ks * 64 + lane) * 8];
            wl[nf][ks] = *(const bf16x8*)&Wpl[wbase + (size_t)(ks * 64 + lane) * 8];
        }
    }
    float bv[2] = {0.f, 0.f};
    if (matsel == 0 && bias) { bv[0] = bias[ncol + l15]; bv[1] = bias[ncol + 16 + l15]; }
    float* __restrict__ C = matsel ? Crel : Croot;

    for (int ch = 0; ch < RPB; ch += 16) {
        const size_t abase = (size_t)((rbase0 + ch) >> 4) * KSTEPS * 512;
        f32x4 acc[2] = {};
        #pragma unroll
        for (int ks = 0; ks < KSTEPS; ++ks) {
            const bf16x8 ah = *(const bf16x8*)&Aph[abase + (size_t)(ks * 64 + lane) * 8];
            const bf16x8 al = *(const bf16x8*)&Apl[abase + (size_t)(ks * 64 + lane) * 8];
            #pragma unroll
            for (int nf = 0; nf < 2; ++nf) {
                acc[nf] = __builtin_amdgcn_mfma_f32_16x16x32_bf16(ah, wh[nf][ks], acc[nf], 0, 0, 0);
                acc[nf] = __builtin_amdgcn_mfma_f32_16x16x32_bf16(al, wh[nf][ks], acc[nf], 0, 0, 0);
                acc[nf] = __builtin_amdgcn_mfma_f32_16x16x32_bf16(ah, wl[nf][ks], acc[nf], 0, 0, 0);
            }
        }
        #pragma unroll
        for (int nf = 0; nf < 2; ++nf) {
            const int col = ncol + nf * 16 + l15;
            #pragma unroll
            for (int j = 0; j < 4; ++j) {
                const int row = rbase0 + ch + rowb + j;
                C[(size_t)row * HH + col] = acc[nf][j] + bv[nf];
            }
        }
    }
}

__device__ __forceinline__
void dev_gemm_pk4(const ushort* __restrict__ X1h, const ushort* __restrict__ X1l,
                  const ushort* __restrict__ X2h, const ushort* __restrict__ X2l,
                  const ushort* __restrict__ X3h, const ushort* __restrict__ X3l,
                  const ushort* __restrict__ X4h, const ushort* __restrict__ X4l,
                  const ushort* __restrict__ Wph, const ushort* __restrict__ Wpl,
                  const float* __restrict__ bias,
                  float* __restrict__ Croot, float* __restrict__ Crel)
{
    const int wid  = threadIdx.x >> 6;
    const int lane = threadIdx.x & 63;
    const int l15  = lane & 15;
    const int matsel = wid >> 2;
    const int ncol = (wid & 3) * 32;
    const int wrg0 = matsel * 8 + (ncol >> 4);
    const int rowb = (lane >> 4) * 4;
    const int rbase0 = blockIdx.x * RPB;
    const ushort* const Ahs[4] = {X1h, X2h, X3h, X4h};
    const ushort* const Als[4] = {X1l, X2l, X3l, X4l};

    f32x4 acc[5][2] = {};
    #pragma unroll
    for (int src = 0; src < 4; ++src) {
        const ushort* __restrict__ Ah_ = Ahs[src];
        const ushort* __restrict__ Al_ = Als[src];
        bf16x8 wh[2][4], wl[2][4];
        #pragma unroll
        for (int nf = 0; nf < 2; ++nf) {
            const size_t wbase = ((size_t)(wrg0 + nf) * 16 + src * 4) * 512;
            #pragma unroll
            for (int ks = 0; ks < 4; ++ks) {
                wh[nf][ks] = *(const bf16x8*)&Wph[wbase + (size_t)(ks * 64 + lane) * 8];
                wl[nf][ks] = *(const bf16x8*)&Wpl[wbase + (size_t)(ks * 64 + lane) * 8];
            }
        }
        #pragma unroll
        for (int ch = 0; ch < 5; ++ch) {
            const size_t abase = (size_t)((rbase0 + ch * 16) >> 4) * 4 * 512;
            #pragma unroll
            for (int ks = 0; ks < 4; ++ks) {
                const bf16x8 ah = *(const bf16x8*)&Ah_[abase + (size_t)(ks * 64 + lane) * 8];
                const bf16x8 al = *(const bf16x8*)&Al_[abase + (size_t)(ks * 64 + lane) * 8];
                #pragma unroll
                for (int nf = 0; nf < 2; ++nf) {
                    acc[ch][nf] = __builtin_amdgcn_mfma_f32_16x16x32_bf16(ah, wh[nf][ks], acc[ch][nf], 0, 0, 0);
                    acc[ch][nf] = __builtin_amdgcn_mfma_f32_16x16x32_bf16(al, wh[nf][ks], acc[ch][nf], 0, 0, 0);
                    acc[ch][nf] = __builtin_amdgcn_mfma_f32_16x16x32_bf16(ah, wl[nf][ks], acc[ch][nf], 0, 0, 0);
                }
            }
        }
    }
    float bv[2] = {0.f, 0.f};
    if (matsel == 0 && bias) { bv[0] = bias[ncol + l15]; bv[1] = bias[ncol + 16 + l15]; }
    float* __restrict__ C = matsel ? Crel : Croot;
    #pragma unroll
    for (int ch = 0; ch < 5; ++ch) {
        #pragma unroll
        for (int nf = 0; nf < 2; ++nf) {
            const int col = ncol + nf * 16 + l15;
            #pragma unroll
            for (int j = 0; j < 4; ++j) {
                const int row = rbase0 + ch * 16 + rowb + j;
                C[(size_t)row * HH + col] = acc[ch][nf][j] + bv[nf];
            }
        }
    }
}

// gather + ReLU + hi/lo split -> packed (5 x 16-node tiles per block)
__device__ __forceinline__
void dev_gather_pk(const float* __restrict__ base, const float* __restrict__ T1,
                   const int* __restrict__ row_ptr, const int* __restrict__ eidx,
                   ushort* __restrict__ Xh, ushort* __restrict__ Xl,
                   ushort (*lds_h)[136], ushort (*lds_l)[136])
{
    const int t = threadIdx.x;
    for (int it = 0; it < 5; ++it) {
        const int nb  = blockIdx.x * RPB + it * 16;
        const int grp = t >> 5;
        const int ln  = t & 31;
        const int n   = nb + grp;
        const int e0 = row_ptr[n], e1 = row_ptr[n + 1];
        float4 a0 = *(const float4*)&base[(size_t)n * HH + ln * 4];
        float4 a1 = {0,0,0,0}, a2 = {0,0,0,0}, a3 = {0,0,0,0};
        int e = e0;
        for (; e + 4 <= e1; e += 4) {
            const int s0 = eidx[e], s1 = eidx[e+1], s2 = eidx[e+2], s3 = eidx[e+3];
            const float4 v0 = *(const float4*)&T1[(size_t)s0 * HH + ln * 4];
            const float4 v1 = *(const float4*)&T1[(size_t)s1 * HH + ln * 4];
            const float4 v2 = *(const float4*)&T1[(size_t)s2 * HH + ln * 4];
            const float4 v3 = *(const float4*)&T1[(size_t)s3 * HH + ln * 4];
            a0.x += v0.x; a0.y += v0.y; a0.z += v0.z; a0.w += v0.w;
            a1.x += v1.x; a1.y += v1.y; a1.z += v1.z; a1.w += v1.w;
            a2.x += v2.x; a2.y += v2.y; a2.z += v2.z; a2.w += v2.w;
            a3.x += v3.x; a3.y += v3.y; a3.z += v3.z; a3.w += v3.w;
        }
        for (; e < e1; ++e) {
            const int s = eidx[e];
            const float4 v = *(const float4*)&T1[(size_t)s * HH + ln * 4];
            a0.x += v.x; a0.y += v.y; a0.z += v.z; a0.w += v.w;
        }
        float v[4];
        v[0] = fmaxf((a0.x + a1.x) + (a2.x + a3.x), 0.f);
        v[1] = fmaxf((a0.y + a1.y) + (a2.y + a3.y), 0.f);
        v[2] = fmaxf((a0.z + a1.z) + (a2.z + a3.z), 0.f);
        v[3] = fmaxf((a0.w + a1.w) + (a2.w + a3.w), 0.f);
        ushort4 h4, l4;
        {
            ushort hh; float hf;
            hh = bf16rn(v[0]); hf = __uint_as_float((uint)hh << 16); h4.x = hh; l4.x = bf16rn(v[0] - hf);
            hh = bf16rn(v[1]); hf = __uint_as_float((uint)hh << 16); h4.y = hh; l4.y = bf16rn(v[1] - hf);
            hh = bf16rn(v[2]); hf = __uint_as_float((uint)hh << 16); h4.z = hh; l4.z = bf16rn(v[2] - hf);
            hh = bf16rn(v[3]); hf = __uint_as_float((uint)hh << 16); h4.w = hh; l4.w = bf16rn(v[3] - hf);
        }
        *(ushort4*)&lds_h[grp][ln * 4] = h4;
        *(ushort4*)&lds_l[grp][ln * 4] = l4;
        __syncthreads();
        const int nl = t & 15;
        const int o  = (t >> 4) & 15;
        const size_t addr = ((size_t)(nb >> 4) * 4 + (o >> 2)) * 512
                          + (size_t)((o & 3) * 16 + nl) * 8;
        if (t < 256) {
            *(uint4*)&Xh[addr] = *(const uint4*)&lds_h[nl][o * 8];
        } else {
            *(uint4*)&Xl[addr] = *(const uint4*)&lds_l[nl][o * 8];
        }
        __syncthreads();
    }
}

__device__ __forceinline__
void dev_gather_f32(const float* __restrict__ T1, const int* __restrict__ row_ptr,
                    const int* __restrict__ eidx, float* __restrict__ X)
{
    const int t = threadIdx.x;
    for (int it = 0; it < 5; ++it) {
        const int n  = blockIdx.x * RPB + it * 16 + (t >> 5);
        const int f4 = t & 31;
        const int e0 = row_ptr[n], e1 = row_ptr[n + 1];
        float4 a0 = *(const float4*)&X[(size_t)n * HH + f4 * 4];
        float4 a1 = {0,0,0,0}, a2 = {0,0,0,0}, a3 = {0,0,0,0};
        int e = e0;
        for (; e + 4 <= e1; e += 4) {
            const int s0 = eidx[e], s1 = eidx[e+1], s2 = eidx[e+2], s3 = eidx[e+3];
            const float4 v0 = *(const float4*)&T1[(size_t)s0 * HH + f4 * 4];
            const float4 v1 = *(const float4*)&T1[(size_t)s1 * HH + f4 * 4];
            const float4 v2 = *(const float4*)&T1[(size_t)s2 * HH + f4 * 4];
            const float4 v3 = *(const float4*)&T1[(size_t)s3 * HH + f4 * 4];
            a0.x += v0.x; a0.y += v0.y; a0.z += v0.z; a0.w += v0.w;
            a1.x += v1.x; a1.y += v1.y; a1.z += v1.z; a1.w += v1.w;
            a2.x += v2.x; a2.y += v2.y; a2.z += v2.z; a2.w += v2.w;
            a3.x += v3.x; a3.y += v3.y; a3.z += v3.z; a3.w += v3.w;
        }
        for (; e < e1; ++e) {
            const int s = eidx[e];
            const float4 v = *(const float4*)&T1[(size_t)s * HH + f4 * 4];
            a0.x += v.x; a0.y += v.y; a0.z += v.z; a0.w += v.w;
        }
        float4 acc;
        acc.x = (a0.x + a1.x) + (a2.x + a3.x);
        acc.y = (a0.y + a1.y) + (a2.y + a3.y);
        acc.z = (a0.z + a1.z) + (a2.z + a3.z);
        acc.w = (a0.w + a1.w) + (a2.w + a3.w);
        *(float4*)&X[(size_t)n * HH + f4 * 4] = acc;
    }
}

// ---------------------------------------------------------------------------
// the cooperative pipeline kernel: 5 GEMMs + 5 gathers + BN + pool + head
// ---------------------------------------------------------------------------
struct PipeArgs {
    const ushort *XPh, *XPl;
    const ushort *W1h, *W1l, *W2h, *W2l, *W3h, *W3l, *W4h, *W4l, *W5h, *W5l;
    const float *b1, *b2, *b3, *b4, *b5;
    float *XR, *T1;
    ushort *X1h, *X1l, *X2h, *X2l, *X3h, *X3l, *X4h, *X4l;
    const int *row_ptr, *eidx, *batch;
    float *STATS, *POOL;
    const float *gamma, *beta, *lin_w, *lin_b;
    float *out;
};

__global__ __launch_bounds__(512)
void pipeline(PipeArgs a)
{
    __shared__ ushort lds_h[16][136];
    __shared__ ushort lds_l[16][136];
    __shared__ float sh_s[4][128];
    __shared__ float sh_q[4][128];
    __shared__ float sh_fin[128];
    __shared__ int seg[2];
    cg::grid_group grid = cg::this_grid();
    const int t = threadIdx.x;

    // layer 1
    dev_gemm_pk<7>(a.XPh, a.XPl, a.W1h, a.W1l, a.b1, a.XR, a.T1);
    grid.sync();
    dev_gather_pk(a.XR, a.T1, a.row_ptr, a.eidx, a.X1h, a.X1l, lds_h, lds_l);
    grid.sync();
    // layer 2
    dev_gemm_pk<4>(a.X1h, a.X1l, a.W2h, a.W2l, a.b2, a.XR, a.T1);
    grid.sync();
    dev_gather_pk(a.XR, a.T1, a.row_ptr, a.eidx, a.X2h, a.X2l, lds_h, lds_l);
    grid.sync();
    // layer 3
    dev_gemm_pk<4>(a.X2h, a.X2l, a.W3h, a.W3l, a.b3, a.XR, a.T1);
    grid.sync();
    dev_gather_pk(a.XR, a.T1, a.row_ptr, a.eidx, a.X3h, a.X3l, lds_h, lds_l);
    grid.sync();
    // layer 4
    dev_gemm_pk<4>(a.X3h, a.X3l, a.W4h, a.W4l, a.b4, a.XR, a.T1);
    grid.sync();
    dev_gather_pk(a.XR, a.T1, a.row_ptr, a.eidx, a.X4h, a.X4l, lds_h, lds_l);
    grid.sync();
    // layer 5 (concat GEMM) then fp32 gather in-place on XR
    dev_gemm_pk4(a.X1h, a.X1l, a.X2h, a.X2l, a.X3h, a.X3l, a.X4h, a.X4l,
                 a.W5h, a.W5l, a.b5, a.XR, a.T1);
    grid.sync();
    dev_gather_f32(a.T1, a.row_ptr, a.eidx, a.XR);
    __syncthreads();    // XR rows of this block are block-local: no grid sync

    // BN stats + per-graph pool over this block's 80 rows
    {
        const int r0 = blockIdx.x * RPB;
        const int f = t & 127, part = t >> 7;
        float s = 0.f, q = 0.f;
        for (int r = r0 + part; r < r0 + RPB; r += 4) {
            const float v = a.XR[(size_t)r * HH + f];
            s += v; q += v * v;
        }
        sh_s[part][f] = s; sh_q[part][f] = q;
        __syncthreads();
        if (t < 128) {
            atomicAdd(&a.STATS[t], sh_s[0][t] + sh_s[1][t] + sh_s[2][t] + sh_s[3][t]);
        } else if (t < 256) {
            const int f2 = t & 127;
            atomicAdd(&a.STATS[128 + f2], sh_q[0][f2] + sh_q[1][f2] + sh_q[2][f2] + sh_q[3][f2]);
        }
        if (t < 128) {
            float acc = 0.f;
            int curg = a.batch[r0];
            for (int n = r0; n < r0 + RPB; ++n) {
                const int g = a.batch[n];
                if (g != curg) {
                    atomicAdd(&a.POOL[(size_t)curg * HH + t], acc);
                    acc = 0.f; curg = g;
                }
                acc += a.XR[(size_t)n * HH + t];
            }
            atomicAdd(&a.POOL[(size_t)curg * HH + t], acc);
        }
    }
    grid.sync();

    // finalize: BN affine on pooled means + linear head (blocks 0..99)
    if (blockIdx.x < GG) {
        const int g = blockIdx.x;
        if (t < 2) {
            const int target = g + t;
            int lo = 0, hi = NN;
            while (lo < hi) {
                const int mid = (lo + hi) >> 1;
                if (a.batch[mid] < target) lo = mid + 1; else hi = mid;
            }
            seg[t] = lo;
        }
        __syncthreads();
        if (t < 128) {
            const float c   = (float)(seg[1] - seg[0]);
            const float mu  = a.STATS[t] * (1.0f / NN);
            const float var = a.STATS[128 + t] * (1.0f / NN) - mu * mu;
            const float scale = a.gamma[t] * rsqrtf(var + BN_EPS);
            const float pm = a.POOL[(size_t)g * HH + t] / fmaxf(c, 1.0f);
            sh_fin[t] = (pm - mu) * scale + a.beta[t];
        }
        __syncthreads();
        if (t < CC) {
            float s = a.lin_b[t];
            #pragma unroll 8
            for (int k = 0; k < HH; ++k) s += sh_fin[k] * a.lin_w[t * HH + k];
            a.out[(size_t)g * CC + t] = s;
        }
    }
}

// ---------------------------------------------------------------------------
// preprocessing kernels (unchanged from R12)
// ---------------------------------------------------------------------------
__global__ void split_w(const float* __restrict__ Wroot, const float* __restrict__ Wrel,
                        int K, int Kp, ushort* __restrict__ Wh, ushort* __restrict__ Wl,
                        int total)
{
    int i = blockIdx.x * blockDim.x + threadIdx.x;
    if (i >= total) return;
    const int row = i / Kp, col = i - row * Kp;
    float v = 0.f;
    if (col < K) v = (row < 128) ? Wroot[row * K + col] : Wrel[(row - 128) * K + col];
    const ushort h = bf16rn(v);
    const float hf = __uint_as_float((uint)h << 16);
    const int ksteps = Kp >> 5;
    const size_t addr = ((size_t)(row >> 4) * ksteps + (col >> 5)) * 512
                      + (size_t)(((col >> 3) & 3) * 16 + (row & 15)) * 8 + (col & 7);
    Wh[addr] = h;
    Wl[addr] = bf16rn(v - hf);
}

__global__ __launch_bounds__(448)
void pack_x(const float* __restrict__ x, ushort* __restrict__ Xh, ushort* __restrict__ Xl)
{
    const int t = threadIdx.x;
    const int n = blockIdx.x * 16 + (t & 15);
    const int o = t >> 4;                   // k-octet 0..27
    float v[8];
    if (o < 25) {
        const float4 a = *(const float4*)&x[(size_t)n * FIN + o * 8];
        const float4 b = *(const float4*)&x[(size_t)n * FIN + o * 8 + 4];
        v[0]=a.x; v[1]=a.y; v[2]=a.z; v[3]=a.w; v[4]=b.x; v[5]=b.y; v[6]=b.z; v[7]=b.w;
    } else {
        #pragma unroll
        for (int j = 0; j < 8; ++j) v[j] = 0.f;
    }
    bf16x8 h, l;
    #pragma unroll
    for (int j = 0; j < 8; ++j) {
        const ushort hh = bf16rn(v[j]);
        h[j] = (short)hh;
        l[j] = (short)bf16rn(v[j] - __uint_as_float((uint)hh << 16));
    }
    const size_t addr = ((size_t)(n >> 4) * 7 + (o >> 2)) * 512
                      + (size_t)((o & 3) * 16 + (n & 15)) * 8;
    *(bf16x8*)&Xh[addr] = h;
    *(bf16x8*)&Xl[addr] = l;
}

__global__ void hist_k(const int* __restrict__ ei, int* __restrict__ deg)
{
    int e = blockIdx.x * blockDim.x + threadIdx.x;
    if (e < EE) atomicAdd(&deg[ei[EE + e]], 1);
}

__global__ __launch_bounds__(1024)
void scan_k(const int* __restrict__ deg, int* __restrict__ row_ptr,
            int* __restrict__ pos)
{
    __shared__ int part[1024];
    const int t = threadIdx.x;
    const int chunk = (NN + 1023) / 1024;
    const int i0 = t * chunk;
    const int i1 = min(i0 + chunk, NN);
    int s = 0;
    for (int i = i0; i < i1; ++i) s += deg[i];
    part[t] = s;
    __syncthreads();
    for (int off = 1; off < 1024; off <<= 1) {
        int v = (t >= off) ? part[t - off] : 0;
        __syncthreads();
        part[t] += v;
        __syncthreads();
    }
    int run = (t == 0) ? 0 : part[t - 1];
    for (int i = i0; i < i1; ++i) {
        const int d = deg[i];
        row_ptr[i] = run;
        pos[i] = run;
        run += d;
    }
    if (t == 0) row_ptr[NN] = part[1023];
}

__global__ void fill_k(const int* __restrict__ ei, int* __restrict__ pos,
                       int* __restrict__ eidx)
{
    int e = blockIdx.x * blockDim.x + threadIdx.x;
    if (e < EE) {
        const int slot = atomicAdd(&pos[ei[EE + e]], 1);
        eidx[slot] = ei[e];
    }
}

__global__ void zero_k(float* __restrict__ p, int n)
{
    int i = blockIdx.x * blockDim.x + threadIdx.x;
    if (i < n) p[i] = 0.f;
}

extern "C" void kernel_launch(void* const* d_in, const int* in_sizes, int n_in,
                              void* d_out, int out_size, void* d_ws, size_t ws_size,
                              hipStream_t stream)
{
    const float* x       = (const float*)d_in[0];
    const int*   ei      = (const int*)d_in[1];
    const int*   batch   = (const int*)d_in[2];
    const float* w1_rel  = (const float*)d_in[3];
    const float* w1_root = (const float*)d_in[4];
    const float* b1      = (const float*)d_in[5];
    const float* w2_rel  = (const float*)d_in[6];
    const float* w2_root = (const float*)d_in[7];
    const float* b2      = (const float*)d_in[8];
    const float* w3_rel  = (const float*)d_in[9];
    const float* w3_root = (const float*)d_in[10];
    const float* b3      = (const float*)d_in[11];
    const float* w4_rel  = (const float*)d_in[12];
    const float* w4_root = (const float*)d_in[13];
    const float* b4      = (const float*)d_in[14];
    const float* w5_rel  = (const float*)d_in[15];   // [128, 512]
    const float* w5_root = (const float*)d_in[16];   // [128, 512]
    const float* b5      = (const float*)d_in[17];
    const float* gamma   = (const float*)d_in[18];
    const float* beta    = (const float*)d_in[19];
    const float* lin_w   = (const float*)d_in[20];
    const float* lin_b   = (const float*)d_in[21];
    float* out = (float*)d_out;

    const size_t NH = (size_t)NN * HH;   // 2,560,000
    float*  XR  = (float*)d_ws;
    float*  T1  = XR + NH;
    ushort* X1h = (ushort*)(T1 + NH);
    ushort* X1l = X1h + NH;
    ushort* X2h = X1l + NH;
    ushort* X2l = X2h + NH;
    ushort* X3h = X2l + NH;
    ushort* X3l = X3h + NH;
    ushort* X4h = X3l + NH;
    ushort* X4l = X4h + NH;
    const int K1P = 224;
    ushort* W1h = X4l + NH;
    ushort* W1l = W1h + 256 * K1P;
    ushort* W2h = W1l + 256 * K1P;
    ushort* W2l = W2h + 256 * 128;
    ushort* W3h = W2l + 256 * 128;
    ushort* W3l = W3h + 256 * 128;
    ushort* W4h = W3l + 256 * 128;
    ushort* W4l = W4h + 256 * 128;
    ushort* W5h = W4l + 256 * 128;
    ushort* W5l = W5h + 256 * 512;
    float*  STATS = (float*)(W5l + 256 * 512);   // 256
    float*  POOL  = STATS + 256;                 // GG*HH
    int* row_ptr = (int*)(POOL + (size_t)GG * HH);
    int* pos     = row_ptr + (NN + 1);
    int* deg     = pos + NN;
    int* eidx    = deg + NN;
    const size_t need = (size_t)(eidx + EE) - (size_t)d_ws;
    if (ws_size < need) return;

    // packed layer-1 input aliases X2h..X3l (dead once L1 GEMM completes)
    ushort* XPh = X2h;
    ushort* XPl = X2h + (size_t)NN * K1P;

    const dim3 blk(256);
    const int gedge = (EE + 255) / 256;
    const int ggpk  = NN / 16;

    zero_k<<<(256 + GG * HH + 255) / 256, blk, 0, stream>>>(STATS, 256 + GG * HH);
    zero_k<<<(NN + 255) / 256, blk, 0, stream>>>((float*)deg, NN);

    // CSR build
    hist_k<<<gedge, blk, 0, stream>>>(ei, deg);
    scan_k<<<1, dim3(1024), 0, stream>>>(deg, row_ptr, pos);
    fill_k<<<gedge, blk, 0, stream>>>(ei, pos, eidx);

    // weight splits (fragment-packed) + layer-1 input pack
    split_w<<<(256 * K1P + 255) / 256, blk, 0, stream>>>(w1_root, w1_rel, FIN, K1P, W1h, W1l, 256 * K1P);
    split_w<<<(256 * 128 + 255) / 256, blk, 0, stream>>>(w2_root, w2_rel, HH, 128, W2h, W2l, 256 * 128);
    split_w<<<(256 * 128 + 255) / 256, blk, 0, stream>>>(w3_root, w3_rel, HH, 128, W3h, W3l, 256 * 128);
    split_w<<<(256 * 128 + 255) / 256, blk, 0, stream>>>(w4_root, w4_rel, HH, 128, W4h, W4l, 256 * 128);
    split_w<<<(256 * 512 + 255) / 256, blk, 0, stream>>>(w5_root, w5_rel, 512, 512, W5h, W5l, 256 * 512);
    pack_x<<<ggpk, dim3(448), 0, stream>>>(x, XPh, XPl);

    // the whole layer pipeline + BN + pool + head: ONE cooperative kernel
    PipeArgs pa;
    pa.XPh = XPh; pa.XPl = XPl;
    pa.W1h = W1h; pa.W1l = W1l; pa.W2h = W2h; pa.W2l = W2l;
    pa.W3h = W3h; pa.W3l = W3l; pa.W4h = W4h; pa.W4l = W4l;
    pa.W5h = W5h; pa.W5l = W5l;
    pa.b1 = b1; pa.b2 = b2; pa.b3 = b3; pa.b4 = b4; pa.b5 = b5;
    pa.XR = XR; pa.T1 = T1;
    pa.X1h = X1h; pa.X1l = X1l; pa.X2h = X2h; pa.X2l = X2l;
    pa.X3h = X3h; pa.X3l = X3l; pa.X4h = X4h; pa.X4l = X4l;
    pa.row_ptr = row_ptr; pa.eidx = eidx; pa.batch = batch;
    pa.STATS = STATS; pa.POOL = POOL;
    pa.gamma = gamma; pa.beta = beta; pa.lin_w = lin_w; pa.lin_b = lin_b;
    pa.out = out;
    void* kargs[] = { &pa };
    hipLaunchCooperativeKernel((const void*)pipeline, dim3(NN / RPB), dim3(512),
                               kargs, 0, stream);
}

// Round 14
// 322.665 us; speedup vs baseline: 2.0482x; 2.0482x over previous
//
#include <hip/hip_runtime.h>

#define NN 20000
#define EE 320000
#define FIN 200
#define HH 128
#define CC 10
#define GG 100
#define BN_EPS 1e-5f
#define RPB 80          // rows per gemm block; 250 blocks x 80 = 20000

typedef __attribute__((ext_vector_type(8))) short bf16x8;
typedef __attribute__((ext_vector_type(4))) float f32x4;

__device__ __forceinline__ ushort bf16rn(float x) {
    uint u = __float_as_uint(x);
    u += 0x7FFFu + ((u >> 16) & 1u);
    return (ushort)(u >> 16);
}

// Fragment-major packing (verified R11/R12):
// elem (r,k) -> ((r>>4)*(K/32) + (k>>5))*512 + (((k>>3)&3)*16 + (r&15))*8 + (k&7)

// ---------------------------------------------------------------------------
// Packed W-in-registers GEMM (verified R12)
// ---------------------------------------------------------------------------
template<int KSTEPS>
__global__ __launch_bounds__(512)
void gemm_pk(const ushort* __restrict__ Aph, const ushort* __restrict__ Apl,
             const ushort* __restrict__ Wph, const ushort* __restrict__ Wpl,
             const float* __restrict__ bias,
             float* __restrict__ Croot, float* __restrict__ Crel)
{
    const int wid  = threadIdx.x >> 6;
    const int lane = threadIdx.x & 63;
    const int l15  = lane & 15;
    const int matsel = wid >> 2;
    const int ncol = (wid & 3) * 32;
    const int wrg0 = matsel * 8 + (ncol >> 4);
    const int rowb = (lane >> 4) * 4;
    const int rbase0 = blockIdx.x * RPB;

    bf16x8 wh[2][KSTEPS], wl[2][KSTEPS];
    #pragma unroll
    for (int nf = 0; nf < 2; ++nf) {
        const size_t wbase = (size_t)(wrg0 + nf) * KSTEPS * 512;
        #pragma unroll
        for (int ks = 0; ks < KSTEPS; ++ks) {
            wh[nf][ks] = *(const bf16x8*)&Wph[wbase + (size_t)(ks * 64 + lane) * 8];
            wl[nf][ks] = *(const bf16x8*)&Wpl[wbase + (size_t)(ks * 64 + lane) * 8];
        }
    }
    float bv[2] = {0.f, 0.f};
    if (matsel == 0 && bias) { bv[0] = bias[ncol + l15]; bv[1] = bias[ncol + 16 + l15]; }
    float* __restrict__ C = matsel ? Crel : Croot;

    for (int ch = 0; ch < RPB; ch += 16) {
        const size_t abase = (size_t)((rbase0 + ch) >> 4) * KSTEPS * 512;
        f32x4 acc[2] = {};
        #pragma unroll
        for (int ks = 0; ks < KSTEPS; ++ks) {
            const bf16x8 ah = *(const bf16x8*)&Aph[abase + (size_t)(ks * 64 + lane) * 8];
            const bf16x8 al = *(const bf16x8*)&Apl[abase + (size_t)(ks * 64 + lane) * 8];
            #pragma unroll
            for (int nf = 0; nf < 2; ++nf) {
                acc[nf] = __builtin_amdgcn_mfma_f32_16x16x32_bf16(ah, wh[nf][ks], acc[nf], 0, 0, 0);
                acc[nf] = __builtin_amdgcn_mfma_f32_16x16x32_bf16(al, wh[nf][ks], acc[nf], 0, 0, 0);
                acc[nf] = __builtin_amdgcn_mfma_f32_16x16x32_bf16(ah, wl[nf][ks], acc[nf], 0, 0, 0);
            }
        }
        #pragma unroll
        for (int nf = 0; nf < 2; ++nf) {
            const int col = ncol + nf * 16 + l15;   // LOCAL column (0..127)
            #pragma unroll
            for (int j = 0; j < 4; ++j) {
                const int row = rbase0 + ch + rowb + j;
                C[(size_t)row * HH + col] = acc[nf][j] + bv[nf];
            }
        }
    }
}

// ---------------------------------------------------------------------------
// Layer-5 packed concat-GEMM (verified R12)
// ---------------------------------------------------------------------------
__global__ __launch_bounds__(512)
void gemm_pk4(const ushort* __restrict__ X1h, const ushort* __restrict__ X1l,
              const ushort* __restrict__ X2h, const ushort* __restrict__ X2l,
              const ushort* __restrict__ X3h, const ushort* __restrict__ X3l,
              const ushort* __restrict__ X4h, const ushort* __restrict__ X4l,
              const ushort* __restrict__ Wph, const ushort* __restrict__ Wpl,
              const float* __restrict__ bias,
              float* __restrict__ Croot, float* __restrict__ Crel)
{
    const int wid  = threadIdx.x >> 6;
    const int lane = threadIdx.x & 63;
    const int l15  = lane & 15;
    const int matsel = wid >> 2;
    const int ncol = (wid & 3) * 32;
    const int wrg0 = matsel * 8 + (ncol >> 4);
    const int rowb = (lane >> 4) * 4;
    const int rbase0 = blockIdx.x * RPB;
    const ushort* const Ahs[4] = {X1h, X2h, X3h, X4h};
    const ushort* const Als[4] = {X1l, X2l, X3l, X4l};

    f32x4 acc[5][2] = {};
    #pragma unroll
    for (int src = 0; src < 4; ++src) {
        const ushort* __restrict__ Ah_ = Ahs[src];
        const ushort* __restrict__ Al_ = Als[src];
        bf16x8 wh[2][4], wl[2][4];
        #pragma unroll
        for (int nf = 0; nf < 2; ++nf) {
            const size_t wbase = ((size_t)(wrg0 + nf) * 16 + src * 4) * 512;
            #pragma unroll
            for (int ks = 0; ks < 4; ++ks) {
                wh[nf][ks] = *(const bf16x8*)&Wph[wbase + (size_t)(ks * 64 + lane) * 8];
                wl[nf][ks] = *(const bf16x8*)&Wpl[wbase + (size_t)(ks * 64 + lane) * 8];
            }
        }
        #pragma unroll
        for (int ch = 0; ch < 5; ++ch) {
            const size_t abase = (size_t)((rbase0 + ch * 16) >> 4) * 4 * 512;
            #pragma unroll
            for (int ks = 0; ks < 4; ++ks) {
                const bf16x8 ah = *(const bf16x8*)&Ah_[abase + (size_t)(ks * 64 + lane) * 8];
                const bf16x8 al = *(const bf16x8*)&Al_[abase + (size_t)(ks * 64 + lane) * 8];
                #pragma unroll
                for (int nf = 0; nf < 2; ++nf) {
                    acc[ch][nf] = __builtin_amdgcn_mfma_f32_16x16x32_bf16(ah, wh[nf][ks], acc[ch][nf], 0, 0, 0);
                    acc[ch][nf] = __builtin_amdgcn_mfma_f32_16x16x32_bf16(al, wh[nf][ks], acc[ch][nf], 0, 0, 0);
                    acc[ch][nf] = __builtin_amdgcn_mfma_f32_16x16x32_bf16(ah, wl[nf][ks], acc[ch][nf], 0, 0, 0);
                }
            }
        }
    }
    float bv[2] = {0.f, 0.f};
    if (matsel == 0 && bias) { bv[0] = bias[ncol + l15]; bv[1] = bias[ncol + 16 + l15]; }
    float* __restrict__ C = matsel ? Crel : Croot;
    #pragma unroll
    for (int ch = 0; ch < 5; ++ch) {
        #pragma unroll
        for (int nf = 0; nf < 2; ++nf) {
            const int col = ncol + nf * 16 + l15;
            #pragma unroll
            for (int j = 0; j < 4; ++j) {
                const int row = rbase0 + ch * 16 + rowb + j;
                C[(size_t)row * HH + col] = acc[ch][nf][j] + bv[nf];
            }
        }
    }
}

// ---------------------------------------------------------------------------
// all 5 weight splits in ONE dispatch (blockIdx range switch)
// blocks: W1 224 | W2 128 | W3 128 | W4 128 | W5 512  (total 1120)
// ---------------------------------------------------------------------------
__global__ __launch_bounds__(256)
void split_all(const float* __restrict__ r1, const float* __restrict__ e1,
               const float* __restrict__ r2, const float* __restrict__ e2,
               const float* __restrict__ r3, const float* __restrict__ e3,
               const float* __restrict__ r4, const float* __restrict__ e4,
               const float* __restrict__ r5, const float* __restrict__ e5,
               ushort* __restrict__ W1h, ushort* __restrict__ W1l,
               ushort* __restrict__ W2h, ushort* __restrict__ W2l,
               ushort* __restrict__ W3h, ushort* __restrict__ W3l,
               ushort* __restrict__ W4h, ushort* __restrict__ W4l,
               ushort* __restrict__ W5h, ushort* __restrict__ W5l)
{
    const int b = blockIdx.x;
    const float *Wroot, *Wrel; int K, Kp, base; ushort *Wh, *Wl;
    if (b < 224)      { Wroot = r1; Wrel = e1; K = FIN; Kp = 224; Wh = W1h; Wl = W1l; base = 0; }
    else if (b < 352) { Wroot = r2; Wrel = e2; K = 128; Kp = 128; Wh = W2h; Wl = W2l; base = 224; }
    else if (b < 480) { Wroot = r3; Wrel = e3; K = 128; Kp = 128; Wh = W3h; Wl = W3l; base = 352; }
    else if (b < 608) { Wroot = r4; Wrel = e4; K = 128; Kp = 128; Wh = W4h; Wl = W4l; base = 480; }
    else              { Wroot = r5; Wrel = e5; K = 512; Kp = 512; Wh = W5h; Wl = W5l; base = 608; }
    const int i = (b - base) * 256 + threadIdx.x;     // grids sized exactly
    const int row = i / Kp, col = i - row * Kp;
    float v = 0.f;
    if (col < K) v = (row < 128) ? Wroot[row * K + col] : Wrel[(row - 128) * K + col];
    const ushort h = bf16rn(v);
    const float hf = __uint_as_float((uint)h << 16);
    const int ksteps = Kp >> 5;
    const size_t addr = ((size_t)(row >> 4) * ksteps + (col >> 5)) * 512
                      + (size_t)(((col >> 3) & 3) * 16 + (row & 15)) * 8 + (col & 7);
    Wh[addr] = h;
    Wl[addr] = bf16rn(v - hf);
}

// ---------------------------------------------------------------------------
// pack layer-1 input (verified R12)
// ---------------------------------------------------------------------------
__global__ __launch_bounds__(448)
void pack_x(const float* __restrict__ x, ushort* __restrict__ Xh, ushort* __restrict__ Xl)
{
    const int t = threadIdx.x;
    const int n = blockIdx.x * 16 + (t & 15);
    const int o = t >> 4;                   // k-octet 0..27
    float v[8];
    if (o < 25) {
        const float4 a = *(const float4*)&x[(size_t)n * FIN + o * 8];
        const float4 b = *(const float4*)&x[(size_t)n * FIN + o * 8 + 4];
        v[0]=a.x; v[1]=a.y; v[2]=a.z; v[3]=a.w; v[4]=b.x; v[5]=b.y; v[6]=b.z; v[7]=b.w;
    } else {
        #pragma unroll
        for (int j = 0; j < 8; ++j) v[j] = 0.f;
    }
    bf16x8 h, l;
    #pragma unroll
    for (int j = 0; j < 8; ++j) {
        const ushort hh = bf16rn(v[j]);
        h[j] = (short)hh;
        l[j] = (short)bf16rn(v[j] - __uint_as_float((uint)hh << 16));
    }
    const size_t addr = ((size_t)(n >> 4) * 7 + (o >> 2)) * 512
                      + (size_t)((o & 3) * 16 + (n & 15)) * 8;
    *(bf16x8*)&Xh[addr] = h;
    *(bf16x8*)&Xl[addr] = l;
}

// ---------------------------------------------------------------------------
// CSR build (verified R12)
// ---------------------------------------------------------------------------
__global__ void hist_k(const int* __restrict__ ei, int* __restrict__ deg)
{
    int e = blockIdx.x * blockDim.x + threadIdx.x;
    if (e < EE) atomicAdd(&deg[ei[EE + e]], 1);
}

__global__ __launch_bounds__(1024)
void scan_k(const int* __restrict__ deg, int* __restrict__ row_ptr,
            int* __restrict__ pos)
{
    __shared__ int part[1024];
    const int t = threadIdx.x;
    const int chunk = (NN + 1023) / 1024;
    const int i0 = t * chunk;
    const int i1 = min(i0 + chunk, NN);
    int s = 0;
    for (int i = i0; i < i1; ++i) s += deg[i];
    part[t] = s;
    __syncthreads();
    for (int off = 1; off < 1024; off <<= 1) {
        int v = (t >= off) ? part[t - off] : 0;
        __syncthreads();
        part[t] += v;
        __syncthreads();
    }
    int run = (t == 0) ? 0 : part[t - 1];
    for (int i = i0; i < i1; ++i) {
        const int d = deg[i];
        row_ptr[i] = run;
        pos[i] = run;
        run += d;
    }
    if (t == 0) row_ptr[NN] = part[1023];
}

__global__ void fill_k(const int* __restrict__ ei, int* __restrict__ pos,
                       int* __restrict__ eidx)
{
    int e = blockIdx.x * blockDim.x + threadIdx.x;
    if (e < EE) {
        const int slot = atomicAdd(&pos[ei[EE + e]], 1);
        eidx[slot] = ei[e];
    }
}

// one zero pass over deg (ints) + STATS/POOL (floats)
__global__ void zero2_k(int* __restrict__ deg, float* __restrict__ sp, int n1, int n2)
{
    int i = blockIdx.x * blockDim.x + threadIdx.x;
    if (i < n1) deg[i] = 0;
    else if (i < n1 + n2) sp[i - n1] = 0.f;
}

// ---------------------------------------------------------------------------
// gather v3 (verified R12): coalesced reads + coalesced packed writes via LDS
// ---------------------------------------------------------------------------
__global__ __launch_bounds__(512)
void gather_pk(const float* __restrict__ base, const float* __restrict__ T1,
               const int* __restrict__ row_ptr, const int* __restrict__ eidx,
               ushort* __restrict__ Xh, ushort* __restrict__ Xl)
{
    __shared__ ushort lds_h[16][136];
    __shared__ ushort lds_l[16][136];
    const int t   = threadIdx.x;
    const int grp = t >> 5;
    const int ln  = t & 31;
    const int n   = blockIdx.x * 16 + grp;

    const int e0 = row_ptr[n], e1 = row_ptr[n + 1];
    float4 a0 = *(const float4*)&base[(size_t)n * HH + ln * 4];
    float4 a1 = {0,0,0,0}, a2 = {0,0,0,0}, a3 = {0,0,0,0};
    int e = e0;
    for (; e + 4 <= e1; e += 4) {
        const int s0 = eidx[e], s1 = eidx[e+1], s2 = eidx[e+2], s3 = eidx[e+3];
        const float4 v0 = *(const float4*)&T1[(size_t)s0 * HH + ln * 4];
        const float4 v1 = *(const float4*)&T1[(size_t)s1 * HH + ln * 4];
        const float4 v2 = *(const float4*)&T1[(size_t)s2 * HH + ln * 4];
        const float4 v3 = *(const float4*)&T1[(size_t)s3 * HH + ln * 4];
        a0.x += v0.x; a0.y += v0.y; a0.z += v0.z; a0.w += v0.w;
        a1.x += v1.x; a1.y += v1.y; a1.z += v1.z; a1.w += v1.w;
        a2.x += v2.x; a2.y += v2.y; a2.z += v2.z; a2.w += v2.w;
        a3.x += v3.x; a3.y += v3.y; a3.z += v3.z; a3.w += v3.w;
    }
    for (; e < e1; ++e) {
        const int s = eidx[e];
        const float4 v = *(const float4*)&T1[(size_t)s * HH + ln * 4];
        a0.x += v.x; a0.y += v.y; a0.z += v.z; a0.w += v.w;
    }
    float v[4];
    v[0] = fmaxf((a0.x + a1.x) + (a2.x + a3.x), 0.f);
    v[1] = fmaxf((a0.y + a1.y) + (a2.y + a3.y), 0.f);
    v[2] = fmaxf((a0.z + a1.z) + (a2.z + a3.z), 0.f);
    v[3] = fmaxf((a0.w + a1.w) + (a2.w + a3.w), 0.f);
    ushort4 h4, l4;
    {
        ushort hh; float hf;
        hh = bf16rn(v[0]); hf = __uint_as_float((uint)hh << 16); h4.x = hh; l4.x = bf16rn(v[0] - hf);
        hh = bf16rn(v[1]); hf = __uint_as_float((uint)hh << 16); h4.y = hh; l4.y = bf16rn(v[1] - hf);
        hh = bf16rn(v[2]); hf = __uint_as_float((uint)hh << 16); h4.z = hh; l4.z = bf16rn(v[2] - hf);
        hh = bf16rn(v[3]); hf = __uint_as_float((uint)hh << 16); h4.w = hh; l4.w = bf16rn(v[3] - hf);
    }
    *(ushort4*)&lds_h[grp][ln * 4] = h4;
    *(ushort4*)&lds_l[grp][ln * 4] = l4;
    __syncthreads();

    const int nl = t & 15;
    const int o  = (t >> 4) & 15;
    const size_t addr = ((size_t)blockIdx.x * 4 + (o >> 2)) * 512
                      + (size_t)((o & 3) * 16 + nl) * 8;
    if (t < 256) {
        *(uint4*)&Xh[addr] = *(const uint4*)&lds_h[nl][o * 8];
    } else {
        *(uint4*)&Xl[addr] = *(const uint4*)&lds_l[nl][o * 8];
    }
}

// ---------------------------------------------------------------------------
// layer-5 gather FUSED with BN-stats and per-graph pooling.
// X5 is needed only by BN/pool -> never materialized. 1250 blocks x 256 thr;
// block owns 16 rows (2 iters x 8 groups x 32 lanes), rows parked in LDS,
// then per-block reduction + atomics into STATS/POOL.
// ---------------------------------------------------------------------------
__global__ __launch_bounds__(256)
void gather_bn(const float* __restrict__ base, const float* __restrict__ T1,
               const int* __restrict__ row_ptr, const int* __restrict__ eidx,
               const int* __restrict__ batch,
               float* __restrict__ stats, float* __restrict__ pool)
{
    __shared__ float vals[16][132];
    __shared__ int bg[16];
    const int t   = threadIdx.x;
    const int grp = t >> 5;
    const int ln  = t & 31;
    const int n0  = blockIdx.x * 16;

    #pragma unroll
    for (int it = 0; it < 2; ++it) {
        const int r = it * 8 + grp;
        const int n = n0 + r;
        const int e0 = row_ptr[n], e1 = row_ptr[n + 1];
        float4 a0 = *(const float4*)&base[(size_t)n * HH + ln * 4];
        float4 a1 = {0,0,0,0}, a2 = {0,0,0,0}, a3 = {0,0,0,0};
        int e = e0;
        for (; e + 4 <= e1; e += 4) {
            const int s0 = eidx[e], s1 = eidx[e+1], s2 = eidx[e+2], s3 = eidx[e+3];
            const float4 v0 = *(const float4*)&T1[(size_t)s0 * HH + ln * 4];
            const float4 v1 = *(const float4*)&T1[(size_t)s1 * HH + ln * 4];
            const float4 v2 = *(const float4*)&T1[(size_t)s2 * HH + ln * 4];
            const float4 v3 = *(const float4*)&T1[(size_t)s3 * HH + ln * 4];
            a0.x += v0.x; a0.y += v0.y; a0.z += v0.z; a0.w += v0.w;
            a1.x += v1.x; a1.y += v1.y; a1.z += v1.z; a1.w += v1.w;
            a2.x += v2.x; a2.y += v2.y; a2.z += v2.z; a2.w += v2.w;
            a3.x += v3.x; a3.y += v3.y; a3.z += v3.z; a3.w += v3.w;
        }
        for (; e < e1; ++e) {
            const int s = eidx[e];
            const float4 v = *(const float4*)&T1[(size_t)s * HH + ln * 4];
            a0.x += v.x; a0.y += v.y; a0.z += v.z; a0.w += v.w;
        }
        vals[r][ln * 4 + 0] = (a0.x + a1.x) + (a2.x + a3.x);
        vals[r][ln * 4 + 1] = (a0.y + a1.y) + (a2.y + a3.y);
        vals[r][ln * 4 + 2] = (a0.z + a1.z) + (a2.z + a3.z);
        vals[r][ln * 4 + 3] = (a0.w + a1.w) + (a2.w + a3.w);
    }
    if (t < 16) bg[t] = batch[n0 + t];
    __syncthreads();

    if (t < 128) {
        float s = 0.f;
        #pragma unroll
        for (int r = 0; r < 16; ++r) s += vals[r][t];
        atomicAdd(&stats[t], s);
        // per-graph pool (rows sorted by graph)
        float acc = 0.f;
        int curg = bg[0];
        #pragma unroll
        for (int r = 0; r < 16; ++r) {
            const int g = bg[r];
            if (g != curg) {
                atomicAdd(&pool[(size_t)curg * HH + t], acc);
                acc = 0.f; curg = g;
            }
            acc += vals[r][t];
        }
        atomicAdd(&pool[(size_t)curg * HH + t], acc);
    } else {
        const int f = t - 128;
        float q = 0.f;
        #pragma unroll
        for (int r = 0; r < 16; ++r) { const float v = vals[r][f]; q += v * v; }
        atomicAdd(&stats[128 + f], q);
    }
}

// BN affine on pooled means + linear head (verified R12)
__global__ __launch_bounds__(128)
void finalize(const float* __restrict__ stats, const float* __restrict__ pool,
              const int* __restrict__ batch,
              const float* __restrict__ gamma, const float* __restrict__ beta,
              const float* __restrict__ lin_w, const float* __restrict__ lin_b,
              float* __restrict__ out)
{
    const int g = blockIdx.x, f = threadIdx.x;
    __shared__ int seg[2];
    if (f < 2) {
        const int target = g + f;
        int lo = 0, hi = NN;
        while (lo < hi) {
            const int mid = (lo + hi) >> 1;
            if (batch[mid] < target) lo = mid + 1; else hi = mid;
        }
        seg[f] = lo;
    }
    __syncthreads();
    const float c   = (float)(seg[1] - seg[0]);
    const float mu  = stats[f] * (1.0f / NN);
    const float var = stats[128 + f] * (1.0f / NN) - mu * mu;
    const float scale = gamma[f] * rsqrtf(var + BN_EPS);
    const float pm = pool[(size_t)g * HH + f] / fmaxf(c, 1.0f);
    __shared__ float sh[128];
    sh[f] = (pm - mu) * scale + beta[f];
    __syncthreads();
    if (f < CC) {
        float s = lin_b[f];
        #pragma unroll 8
        for (int k = 0; k < HH; ++k) s += sh[k] * lin_w[f * HH + k];
        out[(size_t)g * CC + f] = s;
    }
}

extern "C" void kernel_launch(void* const* d_in, const int* in_sizes, int n_in,
                              void* d_out, int out_size, void* d_ws, size_t ws_size,
                              hipStream_t stream)
{
    const float* x       = (const float*)d_in[0];
    const int*   ei      = (const int*)d_in[1];
    const int*   batch   = (const int*)d_in[2];
    const float* w1_rel  = (const float*)d_in[3];
    const float* w1_root = (const float*)d_in[4];
    const float* b1      = (const float*)d_in[5];
    const float* w2_rel  = (const float*)d_in[6];
    const float* w2_root = (const float*)d_in[7];
    const float* b2      = (const float*)d_in[8];
    const float* w3_rel  = (const float*)d_in[9];
    const float* w3_root = (const float*)d_in[10];
    const float* b3      = (const float*)d_in[11];
    const float* w4_rel  = (const float*)d_in[12];
    const float* w4_root = (const float*)d_in[13];
    const float* b4      = (const float*)d_in[14];
    const float* w5_rel  = (const float*)d_in[15];   // [128, 512]
    const float* w5_root = (const float*)d_in[16];   // [128, 512]
    const float* b5      = (const float*)d_in[17];
    const float* gamma   = (const float*)d_in[18];
    const float* beta    = (const float*)d_in[19];
    const float* lin_w   = (const float*)d_in[20];
    const float* lin_b   = (const float*)d_in[21];
    float* out = (float*)d_out;

    const size_t NH = (size_t)NN * HH;   // 2,560,000
    float*  XR  = (float*)d_ws;
    float*  T1  = XR + NH;
    ushort* X1h = (ushort*)(T1 + NH);
    ushort* X1l = X1h + NH;
    ushort* X2h = X1l + NH;
    ushort* X2l = X2h + NH;
    ushort* X3h = X2l + NH;
    ushort* X3l = X3h + NH;
    ushort* X4h = X3l + NH;
    ushort* X4l = X4h + NH;
    const int K1P = 224;
    ushort* W1h = X4l + NH;
    ushort* W1l = W1h + 256 * K1P;
    ushort* W2h = W1l + 256 * K1P;
    ushort* W2l = W2h + 256 * 128;
    ushort* W3h = W2l + 256 * 128;
    ushort* W3l = W3h + 256 * 128;
    ushort* W4h = W3l + 256 * 128;
    ushort* W4l = W4h + 256 * 128;
    ushort* W5h = W4l + 256 * 128;
    ushort* W5l = W5h + 256 * 512;
    float*  STATS = (float*)(W5l + 256 * 512);   // 256
    float*  POOL  = STATS + 256;                 // GG*HH
    int* row_ptr = (int*)(POOL + (size_t)GG * HH);
    int* pos     = row_ptr + (NN + 1);
    int* deg     = pos + NN;
    int* eidx    = deg + NN;
    const size_t need = (size_t)(eidx + EE) - (size_t)d_ws;
    if (ws_size < need) return;

    // packed layer-1 input aliases X2h..X3l (dead once L1 GEMM completes)
    ushort* XPh = X2h;
    ushort* XPl = X2h + (size_t)NN * K1P;

    const dim3 blk(256);
    const int ggw   = NN / RPB;             // 250 blocks x 512 thr
    const int gedge = (EE + 255) / 256;
    const int ggpk  = NN / 16;              // 1250 blocks

    // single zero pass: deg (ints) + STATS/POOL (floats)
    const int nz = NN + 256 + GG * HH;
    zero2_k<<<(nz + 255) / 256, blk, 0, stream>>>(deg, STATS, NN, 256 + GG * HH);

    // CSR build
    hist_k<<<gedge, blk, 0, stream>>>(ei, deg);
    scan_k<<<1, dim3(1024), 0, stream>>>(deg, row_ptr, pos);
    fill_k<<<gedge, blk, 0, stream>>>(ei, pos, eidx);

    // all weight splits in one dispatch + layer-1 input pack
    split_all<<<1120, blk, 0, stream>>>(w1_root, w1_rel, w2_root, w2_rel,
                                        w3_root, w3_rel, w4_root, w4_rel,
                                        w5_root, w5_rel,
                                        W1h, W1l, W2h, W2l, W3h, W3l,
                                        W4h, W4l, W5h, W5l);
    pack_x<<<ggpk, dim3(448), 0, stream>>>(x, XPh, XPl);

    // layer 1 (K=224 packed)
    gemm_pk<7><<<ggw, dim3(512), 0, stream>>>(XPh, XPl, W1h, W1l, b1, XR, T1);
    gather_pk<<<ggpk, dim3(512), 0, stream>>>(XR, T1, row_ptr, eidx, X1h, X1l);
    // layers 2-4 (K=128 packed)
    gemm_pk<4><<<ggw, dim3(512), 0, stream>>>(X1h, X1l, W2h, W2l, b2, XR, T1);
    gather_pk<<<ggpk, dim3(512), 0, stream>>>(XR, T1, row_ptr, eidx, X2h, X2l);
    gemm_pk<4><<<ggw, dim3(512), 0, stream>>>(X2h, X2l, W3h, W3l, b3, XR, T1);
    gather_pk<<<ggpk, dim3(512), 0, stream>>>(XR, T1, row_ptr, eidx, X3h, X3l);
    gemm_pk<4><<<ggw, dim3(512), 0, stream>>>(X3h, X3l, W4h, W4l, b4, XR, T1);
    gather_pk<<<ggpk, dim3(512), 0, stream>>>(XR, T1, row_ptr, eidx, X4h, X4l);
    // layer 5: packed concat GEMM, then fused gather+BN+pool (X5 never stored)
    gemm_pk4<<<ggw, dim3(512), 0, stream>>>(X1h, X1l, X2h, X2l, X3h, X3l, X4h, X4l,
                                            W5h, W5l, b5, XR, T1);
    gather_bn<<<ggpk, blk, 0, stream>>>(XR, T1, row_ptr, eidx, batch, STATS, POOL);

    // epilogue
    finalize<<<GG, dim3(128), 0, stream>>>(STATS, POOL, batch, gamma, beta, lin_w, lin_b, out);
}